// Round 15
// baseline (498.249 us; speedup 1.0000x reference)
//
#include <hip/hip_runtime.h>

#define B_SZ   512
#define IN_F   256
#define OUT_F  256
#define NINT   15
#define IHALF  128            // input features per block (IN-dim split in 2)
#define NC4    (IHALF * NINT) // float4 coeff entries per block = 1920

typedef const __attribute__((address_space(1))) void gvoid_t;
typedef __attribute__((address_space(3))) void lvoid_t;

template<bool DEP>
__device__ __forceinline__ float kan_eval(float wv, float xv,
                                          const float4* __restrict__ sc, int cbase) {
    const float kD = 2.0f / 15.0f;                 // fl32(2/15), XLA delta bits
    float wx = wv * xv;                            // ref's exact f32 product
    float xc = fminf(fmaxf(wx, -1.0f), 1.0f);
    float u  = __builtin_fmaf(xc, 7.5f, 7.4999f);  // down-biased floor guess
    int   i0 = (int)u;
    float f0 = (float)i0;
    float blo = __fadd_rn(__fmul_rn(f0, kD), -1.0f);
    float bhi = __fadd_rn(__fmul_rn(__fadd_rn(f0, 1.0f), kD), -1.0f);
    bool  up = (xc >= bhi);                        // exact searchsorted(right)-1
    int   j  = i0 + (up ? 1 : 0);
    float bj = up ? bhi : blo;
    float dx = xc - bj;                            // ref's exact f32 sub
    float4 c = sc[cbase + (DEP ? j : 7)];          // DEP: real gather / !DEP: uniform
    return __builtin_fmaf(__builtin_fmaf(__builtin_fmaf(c.w, dx, c.z), dx, c.y), dx, c.x);
}

// ---- main: R6 structure, but 1024-thread blocks -> 32 waves/CU at the SAME
// staging & atomic cost. g-split: 2 threads per batch row, 64 features each. ----
__global__ __launch_bounds__(1024, 8)
void kan_kernel(const float* __restrict__ x, const float* __restrict__ w,
                const float* __restrict__ bias, const float* __restrict__ coeffs,
                float* __restrict__ out)
{
    __shared__ float4 sc[NC4];          // 30720 B
    __shared__ float4 sw4[IHALF / 4];   // 512 B
    __shared__ float  spart[512];       // 2 KB: g=1 partials

    const int o = blockIdx.x >> 1, h = blockIdx.x & 1;
    const int t = threadIdx.x;
    const int b = t & 511;              // batch row
    const int g = t >> 9;               // feature half within block (0/1)

    const float4* gsrc = reinterpret_cast<const float4*>(coeffs)
                         + ((size_t)o * IN_F + h * IHALF) * NINT;
    // stage 1920 float4s with 1024 threads: full pass + 896 (14 whole waves)
    __builtin_amdgcn_global_load_lds((gvoid_t*)(gsrc + t), (lvoid_t*)(sc + t), 16, 0, 0);
    if (t < NC4 - 1024)
        __builtin_amdgcn_global_load_lds((gvoid_t*)(gsrc + t + 1024),
                                         (lvoid_t*)(sc + t + 1024), 16, 0, 0);
    if (t < IHALF / 4)
        sw4[t] = reinterpret_cast<const float4*>(w + (size_t)o * IN_F + h * IHALF)[t];
    __syncthreads();

    const float4* xrow = reinterpret_cast<const float4*>(
        x + (size_t)b * IN_F + h * IHALF + g * (IHALF / 2));
    float a0 = 0.f, a1 = 0.f, a2 = 0.f, a3 = 0.f;

    #pragma unroll 4
    for (int i4 = 0; i4 < IHALF / 8; ++i4) {       // 16 quads = 64 features
        float4 xv = xrow[i4];
        float4 wv = sw4[g * (IHALF / 8) + i4];
        int cb = (g * (IHALF / 8) + i4) * 4 * NINT;
        a0 += kan_eval<true>(wv.x, xv.x, sc, cb);
        a1 += kan_eval<true>(wv.y, xv.y, sc, cb + NINT);
        a2 += kan_eval<true>(wv.z, xv.z, sc, cb + 2 * NINT);
        a3 += kan_eval<true>(wv.w, xv.w, sc, cb + 3 * NINT);
    }
    float acc = (a0 + a1) + (a2 + a3);

    if (g == 1) spart[b] = acc;
    __syncthreads();
    if (g == 0) {
        acc += spart[b];
        if (h == 0) acc += bias[o];
        // out zeroed by memset; exactly 2 commutative adds from exact 0 per elt.
        atomicAdd(out + (size_t)b * OUT_F + o, acc);
    }
}

// ---- diagnostics: stage once + 8 amplified eval passes; DEP toggles ONLY the
// gather address. Rotating (xi,wi) pairing defeats CSE; asm keeps acc live. ----
template<bool DEP>
__global__ __launch_bounds__(512, 4)
void kab_eval(const float* __restrict__ x, const float* __restrict__ w,
              const float* __restrict__ coeffs)
{
    __shared__ float4 sc[NC4];
    __shared__ float4 sw4[IHALF / 4];
    const int o = blockIdx.x >> 1, h = blockIdx.x & 1, b = threadIdx.x;
    const float4* gsrc = reinterpret_cast<const float4*>(coeffs)
                         + ((size_t)o * IN_F + h * IHALF) * NINT;
    #pragma unroll
    for (int k = 0; k < 4; ++k) {
        int t = b + k * 512;
        if (t < NC4)
            __builtin_amdgcn_global_load_lds((gvoid_t*)(gsrc + t), (lvoid_t*)(sc + t), 16, 0, 0);
    }
    if (b < IHALF / 4)
        sw4[b] = reinterpret_cast<const float4*>(w + (size_t)o * IN_F + h * IHALF)[b];
    __syncthreads();

    const float4* xrow = reinterpret_cast<const float4*>(x + (size_t)b * IN_F + h * IHALF);
    float a0 = 0.f, a1 = 0.f, a2 = 0.f, a3 = 0.f;
    #pragma unroll 1
    for (int r = 0; r < 8; ++r) {
        #pragma unroll 4
        for (int i4 = 0; i4 < IHALF / 4; ++i4) {
            int xi = (i4 + r) & (IHALF / 4 - 1);
            int wi = (3 * i4 + r) & (IHALF / 4 - 1);
            float4 xv = xrow[xi];
            float4 wv = sw4[wi];
            int cb = xi * 4 * NINT;
            a0 += kan_eval<DEP>(wv.x, xv.x, sc, cb);
            a1 += kan_eval<DEP>(wv.y, xv.y, sc, cb + NINT);
            a2 += kan_eval<DEP>(wv.z, xv.z, sc, cb + 2 * NINT);
            a3 += kan_eval<DEP>(wv.w, xv.w, sc, cb + 3 * NINT);
        }
    }
    float acc = (a0 + a1) + (a2 + a3);
    asm volatile("" :: "v"(acc));    // keep-alive, no store
}

extern "C" void kernel_launch(void* const* d_in, const int* in_sizes, int n_in,
                              void* d_out, int out_size, void* d_ws, size_t ws_size,
                              hipStream_t stream) {
    (void)d_ws; (void)ws_size;

    const float *x = nullptr, *wgt = nullptr, *bias = nullptr, *coeffs = nullptr;
    for (int i = 0; i < n_in; ++i) {
        switch (in_sizes[i]) {
            case 512 * 256:           x      = (const float*)d_in[i]; break;
            case 256 * 256:           wgt    = (const float*)d_in[i]; break;
            case 256:                 bias   = (const float*)d_in[i]; break;
            case 256 * 256 * 15 * 4:  coeffs = (const float*)d_in[i]; break;
            default: break;
        }
    }

    hipMemsetAsync(d_out, 0, (size_t)out_size * sizeof(float), stream);
    kan_kernel<<<2 * OUT_F, 1024, 0, stream>>>(x, wgt, bias, coeffs, (float*)d_out);
    // diagnostics (outputs unused; rocprof per-dispatch durations are the data)
    kab_eval<false><<<2 * OUT_F, B_SZ, 0, stream>>>(x, wgt, coeffs);
    kab_eval<true><<<2 * OUT_F, B_SZ, 0, stream>>>(x, wgt, coeffs);
}

// Round 16
// 36.192 us; speedup vs baseline: 13.7668x; 13.7668x over previous
//
#include <hip/hip_runtime.h>

#define IN_F   256
#define OUT_F  256
#define NINT   15
#define IHALF  128            // input features per block (IN-dim split in 2)
#define NC4    (IHALF * NINT) // float4 coeff entries per block = 1920

typedef const __attribute__((address_space(1))) void gvoid_t;
typedef __attribute__((address_space(3))) void lvoid_t;

__device__ __forceinline__ float kan_eval(float wv, float xv,
                                          const float4* __restrict__ sc, int cbase) {
    const float kD = 2.0f / 15.0f;                 // fl32(2/15), XLA delta bits
    float wx = wv * xv;                            // ref's exact f32 product
    float xc = fminf(fmaxf(wx, -1.0f), 1.0f);
    float u  = __builtin_fmaf(xc, 7.5f, 7.4999f);  // down-biased floor guess
    int   i0 = (int)u;                             // ∈ [0,14]
    float f0 = (float)i0;
    float blo = __fadd_rn(__fmul_rn(f0, kD), -1.0f);                   // bp[i0]
    float bhi = __fadd_rn(__fmul_rn(__fadd_rn(f0, 1.0f), kD), -1.0f);  // bp[i0+1]
    bool  up = (xc >= bhi);                        // exact searchsorted(right)-1
    int   j  = i0 + (up ? 1 : 0);                  // j<=14 automatic: bp[15] > 1 >= xc
    float bj = up ? bhi : blo;
    float dx = xc - bj;                            // ref's exact f32 sub
    float4 c = sc[cbase + j];
    return __builtin_fmaf(__builtin_fmaf(__builtin_fmaf(c.w, dx, c.z), dx, c.y), dx, c.x);
}

// R6 structure with 1024-thread blocks: 2 blocks/CU -> 32 waves/CU (8/SIMD),
// at IDENTICAL staging and atomic cost (the clean occupancy experiment).
// g-split: 2 threads per batch row, 64 features each; partials merged in LDS.
__global__ __launch_bounds__(1024, 8)
void kan_kernel(const float* __restrict__ x, const float* __restrict__ w,
                const float* __restrict__ bias, const float* __restrict__ coeffs,
                float* __restrict__ out)
{
    __shared__ float4 sc[NC4];          // 30720 B
    __shared__ float4 sw4[IHALF / 4];   // 512 B
    __shared__ float  spart[512];       // 2 KB: g=1 partials

    const int o = blockIdx.x >> 1, h = blockIdx.x & 1;
    const int t = threadIdx.x;
    const int b = t & 511;              // batch row
    const int g = t >> 9;               // feature half within block (0/1)

    const float4* gsrc = reinterpret_cast<const float4*>(coeffs)
                         + ((size_t)o * IN_F + h * IHALF) * NINT;
    // stage 1920 float4s with 1024 threads: full pass + 896 (14 whole waves)
    __builtin_amdgcn_global_load_lds((gvoid_t*)(gsrc + t), (lvoid_t*)(sc + t), 16, 0, 0);
    if (t < NC4 - 1024)
        __builtin_amdgcn_global_load_lds((gvoid_t*)(gsrc + t + 1024),
                                         (lvoid_t*)(sc + t + 1024), 16, 0, 0);
    if (t < IHALF / 4)
        sw4[t] = reinterpret_cast<const float4*>(w + (size_t)o * IN_F + h * IHALF)[t];
    __syncthreads();

    const float4* xrow = reinterpret_cast<const float4*>(
        x + (size_t)b * IN_F + h * IHALF + g * (IHALF / 2));
    float a0 = 0.f, a1 = 0.f, a2 = 0.f, a3 = 0.f;

    #pragma unroll 4
    for (int i4 = 0; i4 < IHALF / 8; ++i4) {       // 16 quads = 64 features
        float4 xv = xrow[i4];
        float4 wv = sw4[g * (IHALF / 8) + i4];
        int cb = (g * (IHALF / 8) + i4) * 4 * NINT;
        a0 += kan_eval(wv.x, xv.x, sc, cb);
        a1 += kan_eval(wv.y, xv.y, sc, cb + NINT);
        a2 += kan_eval(wv.z, xv.z, sc, cb + 2 * NINT);
        a3 += kan_eval(wv.w, xv.w, sc, cb + 3 * NINT);
    }
    float acc = (a0 + a1) + (a2 + a3);

    if (g == 1) spart[b] = acc;
    __syncthreads();
    if (g == 0) {
        acc += spart[b];
        if (h == 0) acc += bias[o];
        // out zeroed by memset; exactly 2 commutative adds from exact 0 per elt.
        atomicAdd(out + (size_t)b * OUT_F + o, acc);
    }
}

extern "C" void kernel_launch(void* const* d_in, const int* in_sizes, int n_in,
                              void* d_out, int out_size, void* d_ws, size_t ws_size,
                              hipStream_t stream) {
    (void)d_ws; (void)ws_size;

    const float *x = nullptr, *wgt = nullptr, *bias = nullptr, *coeffs = nullptr;
    for (int i = 0; i < n_in; ++i) {
        switch (in_sizes[i]) {
            case 512 * 256:           x      = (const float*)d_in[i]; break;
            case 256 * 256:           wgt    = (const float*)d_in[i]; break;
            case 256:                 bias   = (const float*)d_in[i]; break;
            case 256 * 256 * 15 * 4:  coeffs = (const float*)d_in[i]; break;
            default: break;
        }
    }

    hipMemsetAsync(d_out, 0, (size_t)out_size * sizeof(float), stream);
    kan_kernel<<<2 * OUT_F, 1024, 0, stream>>>(x, wgt, bias, coeffs, (float*)d_out);
}